// Round 5
// baseline (767.606 us; speedup 1.0000x reference)
//
#include <hip/hip_runtime.h>
#include <hip/hip_bf16.h>

#define M_DIM 8192
#define N_DIM 11008
#define K_DIM 4096

typedef __attribute__((ext_vector_type(8))) short bf16x8;
typedef __attribute__((ext_vector_type(4))) float f32x4;

__device__ __forceinline__ short f2bf(float f) {
    __hip_bfloat16 h = __float2bfloat16(f);  // RNE
    short s;
    __builtin_memcpy(&s, &h, sizeof(s));
    return s;
}

__device__ __forceinline__ void gload_lds16(const void* g, void* l) {
    __builtin_amdgcn_global_load_lds(
        (const __attribute__((address_space(1))) unsigned int*)g,
        (__attribute__((address_space(3))) unsigned int*)l, 16, 0, 0);
}

#define MFMA16(A, Bv, C) __builtin_amdgcn_mfma_f32_16x16x32_bf16((A), (Bv), (C), 0, 0, 0)

// ---------------- pass 1: conversion kernels ----------------

__global__ __launch_bounds__(256)
void cvt_x_bf16(const float* __restrict__ X, short* __restrict__ Xb, int n8) {
    int i = blockIdx.x * blockDim.x + threadIdx.x;
    const int stride = gridDim.x * blockDim.x;
    for (; i < n8; i += stride) {
        const float4* p = reinterpret_cast<const float4*>(X + (size_t)i * 8);
        float4 a = p[0], b = p[1];
        bf16x8 v;
        v[0] = f2bf(a.x); v[1] = f2bf(a.y); v[2] = f2bf(a.z); v[3] = f2bf(a.w);
        v[4] = f2bf(b.x); v[5] = f2bf(b.y); v[6] = f2bf(b.z); v[7] = f2bf(b.w);
        *reinterpret_cast<bf16x8*>(Xb + (size_t)i * 8) = v;
    }
}

__global__ __launch_bounds__(256)
void cvt_w_bf16(const int* __restrict__ W, short* __restrict__ Wb, int n8) {
    int i = blockIdx.x * blockDim.x + threadIdx.x;
    const int stride = gridDim.x * blockDim.x;
    for (; i < n8; i += stride) {
        const int4* p = reinterpret_cast<const int4*>(W + (size_t)i * 8);
        int4 a = p[0], b = p[1];
        bf16x8 v;  // int8-range values exact in bf16
        v[0] = f2bf((float)a.x); v[1] = f2bf((float)a.y);
        v[2] = f2bf((float)a.z); v[3] = f2bf((float)a.w);
        v[4] = f2bf((float)b.x); v[5] = f2bf((float)b.y);
        v[6] = f2bf((float)b.z); v[7] = f2bf((float)b.w);
        *reinterpret_cast<bf16x8*>(Wb + (size_t)i * 8) = v;
    }
}

// ---------------- pass 2: 256x256 bf16 GEMM, overlapped-read schedule ----
// 8 waves (2Mx4N), BK=64, 2 LDS tile-buffers (128 KiB), chunk-XOR swizzle
// via pre-swizzled global_load_lds source. All 24 fragment ds_reads issued
// up front (compiler inserts counted lgkmcnt before each consuming MFMA),
// 64 MFMAs stream behind them; only 2 barriers/tile (staging protocol).
// Counted vmcnt(4) at tile end — never drained to 0 in the main loop.

#define STA(T, B, H) do { \
    const short* s_ = gA + (size_t)((H) * 128) * K_DIM + (T) * 64; \
    char* d_ = As + (B) * 32768 + (H) * 16384 + aw; \
    gload_lds16(s_, d_); \
    gload_lds16(s_ + (size_t)64 * K_DIM, d_ + 8192); \
} while (0)

#define STB(T, B, H) do { \
    const short* s_ = gB + (size_t)((H) * 128) * K_DIM + (T) * 64; \
    char* d_ = Bs + (B) * 32768 + (H) * 16384 + aw; \
    gload_lds16(s_, d_); \
    gload_lds16(s_ + (size_t)64 * K_DIM, d_ + 8192); \
} while (0)

// MODE: 0 = steady (issue A t+1, B t+2, vmcnt(4))
//       1 = t==62 (issue A t+1 only, vmcnt(0))
//       2 = t==63 (no issues, no trailing sync)
#define TILE_BODY(T, B, MODE) do { \
    const char* Ab_ = As + (B) * 32768; \
    const char* Bb_ = Bs + (B) * 32768; \
    bf16x8 a0_[4][2], a1_[4][2], b0_[2][2], b1_[2][2]; \
    /* issue a0 (8), b0 (4), b1 (4) reads */ \
    _Pragma("unroll") for (int m = 0; m < 4; ++m) { \
        a0_[m][0] = *(const bf16x8*)(Ab_ + fa + m * 2048 + cs0); \
        a0_[m][1] = *(const bf16x8*)(Ab_ + fa + m * 2048 + cs1); } \
    _Pragma("unroll") for (int n = 0; n < 2; ++n) { \
        b0_[n][0] = *(const bf16x8*)(Bb_ + fb + n * 2048 + cs0); \
        b0_[n][1] = *(const bf16x8*)(Bb_ + fb + n * 2048 + cs1); \
        b1_[n][0] = *(const bf16x8*)(Bb_ + fb + (n + 2) * 2048 + cs0); \
        b1_[n][1] = *(const bf16x8*)(Bb_ + fb + (n + 2) * 2048 + cs1); } \
    if ((MODE) < 2) { STA((T) + 1, 1 - (B), 0); STA((T) + 1, 1 - (B), 1); } \
    /* ph0: m0-3 x n0-1 (overlaps remaining reads) */ \
    _Pragma("unroll") for (int m = 0; m < 4; ++m) \
    _Pragma("unroll") for (int n = 0; n < 2; ++n) { \
        acc[m][n] = MFMA16(a0_[m][0], b0_[n][0], acc[m][n]); \
        acc[m][n] = MFMA16(a0_[m][1], b0_[n][1], acc[m][n]); } \
    /* issue a1 (8) reads — overlap ph1 MFMAs */ \
    _Pragma("unroll") for (int m = 0; m < 4; ++m) { \
        a1_[m][0] = *(const bf16x8*)(Ab_ + fa + (m + 4) * 2048 + cs0); \
        a1_[m][1] = *(const bf16x8*)(Ab_ + fa + (m + 4) * 2048 + cs1); } \
    /* ph1: m0-3 x n2-3 */ \
    _Pragma("unroll") for (int m = 0; m < 4; ++m) \
    _Pragma("unroll") for (int n = 0; n < 2; ++n) { \
        acc[m][n + 2] = MFMA16(a0_[m][0], b1_[n][0], acc[m][n + 2]); \
        acc[m][n + 2] = MFMA16(a0_[m][1], b1_[n][1], acc[m][n + 2]); } \
    /* all waves' tile-t LDS reads must be SERVICED before B-region rewrite */ \
    asm volatile("s_waitcnt lgkmcnt(0)" ::: "memory"); \
    asm volatile("s_barrier" ::: "memory"); \
    if ((MODE) == 0) STB((T) + 2, (B), 0); \
    /* ph2: m4-7 x n0-1 */ \
    _Pragma("unroll") for (int m = 0; m < 4; ++m) \
    _Pragma("unroll") for (int n = 0; n < 2; ++n) { \
        acc[m + 4][n] = MFMA16(a1_[m][0], b0_[n][0], acc[m + 4][n]); \
        acc[m + 4][n] = MFMA16(a1_[m][1], b0_[n][1], acc[m + 4][n]); } \
    if ((MODE) == 0) STB((T) + 2, (B), 1); \
    /* ph3: m4-7 x n2-3 */ \
    _Pragma("unroll") for (int m = 0; m < 4; ++m) \
    _Pragma("unroll") for (int n = 0; n < 2; ++n) { \
        acc[m + 4][n + 2] = MFMA16(a1_[m][0], b1_[n][0], acc[m + 4][n + 2]); \
        acc[m + 4][n + 2] = MFMA16(a1_[m][1], b1_[n][1], acc[m + 4][n + 2]); } \
    if ((MODE) < 2) { \
        asm volatile("s_waitcnt lgkmcnt(0)" ::: "memory"); \
        if ((MODE) == 0) asm volatile("s_waitcnt vmcnt(4)" ::: "memory"); \
        else             asm volatile("s_waitcnt vmcnt(0)" ::: "memory"); \
        asm volatile("s_barrier" ::: "memory"); } \
} while (0)

__global__ __launch_bounds__(512, 2)
void gemm_bf16_ovl(const short* __restrict__ Xb, const short* __restrict__ Wb,
                   const float* __restrict__ SC, float* __restrict__ Out)
{
    __shared__ __attribute__((aligned(16))) char smem[131072];
    char* const As = smem;           // [2][256 rows][128 B], chunk-swizzled
    char* const Bs = smem + 65536;

    const int tid  = threadIdx.x;
    const int lane = tid & 63;
    const int w    = tid >> 6;   // 0..7
    const int wr   = w >> 2;     // 0..1
    const int wc   = w & 3;      // 0..3

    // XCD-aware bijective swizzle: nwg = 1376 = 8 * 172
    const int wg  = blockIdx.x;
    const int swz = (wg & 7) * 172 + (wg >> 3);
    const int by  = swz / 43;
    const int bx  = swz - by * 43;
    const int brow = by * 256;
    const int bcol = bx * 256;

    // staging: lane covers row (w*8 + lane/8), swizzled chunk (lane&7)^(lane>>3)
    const int lr = lane >> 3;
    const int lc = (lane & 7) ^ lr;
    const short* gA = Xb + (size_t)(brow + w * 8 + lr) * K_DIM + (lc << 3);
    const short* gB = Wb + (size_t)(bcol + w * 8 + lr) * K_DIM + (lc << 3);
    const int aw = w * 1024;  // wave rows offset in LDS dest (w*8 rows * 128B)

    // fragment read bases (byte offsets); chunk-XOR matches staging swizzle
    const int fa  = (wr * 128 + (lane & 15)) * 128;
    const int fb  = (wc * 64  + (lane & 15)) * 128;
    const int cs0 = (((lane >> 4) + 0) ^ (lane & 7)) * 16;
    const int cs1 = (((lane >> 4) + 4) ^ (lane & 7)) * 16;

    f32x4 acc[8][4] = {};

    // prologue: tile0 {B0,B1,A0,A1}, tile1 {B0,B1}; certify tile0, B(1) in flight
    STB(0, 0, 0); STB(0, 0, 1); STA(0, 0, 0); STA(0, 0, 1);
    STB(1, 1, 0); STB(1, 1, 1);
    asm volatile("s_waitcnt vmcnt(4)" ::: "memory");
    asm volatile("s_barrier" ::: "memory");

    for (int t = 0; t < 62; t += 2) {
        TILE_BODY(t, 0, 0);
        TILE_BODY(t + 1, 1, 0);
    }
    TILE_BODY(62, 0, 1);
    TILE_BODY(63, 1, 2);

    // epilogue: per-out-channel scale, fp32 store
    // C/D layout: col = lane&15, row = (lane>>4)*4 + j
    const int orow0 = brow + wr * 128 + ((lane >> 4) << 2);
    const int ocol0 = bcol + wc * 64 + (lane & 15);
    #pragma unroll
    for (int n = 0; n < 4; ++n) {
        const float sc = SC[ocol0 + n * 16];
        #pragma unroll
        for (int m = 0; m < 8; ++m)
            #pragma unroll
            for (int j = 0; j < 4; ++j)
                Out[(size_t)(orow0 + m * 16 + j) * N_DIM + (ocol0 + n * 16)]
                    = acc[m][n][j] * sc;
    }
}

// ---------------- fallback: fused single-pass (if ws too small) ----------------

__global__ __launch_bounds__(256, 2)
void wo_int8_gemm_fused(const float* __restrict__ X, const int* __restrict__ W,
                        const float* __restrict__ SC, float* __restrict__ Out)
{
    __shared__ short Asf[128 * 64];
    __shared__ short Bsf[128 * 64];

    const int tid  = threadIdx.x;
    const int lane = tid & 63;
    const int wid  = tid >> 6;
    const int wrf  = wid >> 1;
    const int wcf  = wid & 1;
    const int brow = blockIdx.y * 128;
    const int bcol = blockIdx.x * 128;
    const int srow = tid >> 3;
    const int scol = (tid & 7) << 3;
    const int arow   = wrf * 64 + (lane & 15);
    const int brow_f = wcf * 64 + (lane & 15);
    const int koff   = (lane >> 4) << 3;

    f32x4 acc[4][4] = {};

    for (int k0 = 0; k0 < K_DIM; k0 += 64) {
        __syncthreads();
        #pragma unroll
        for (int p = 0; p < 4; ++p) {
            const int r = p * 32 + srow;
            const float4* xs = reinterpret_cast<const float4*>(
                X + (size_t)(brow + r) * K_DIM + (k0 + scol));
            float4 a0 = xs[0], a1 = xs[1];
            bf16x8 v;
            v[0] = f2bf(a0.x); v[1] = f2bf(a0.y); v[2] = f2bf(a0.z); v[3] = f2bf(a0.w);
            v[4] = f2bf(a1.x); v[5] = f2bf(a1.y); v[6] = f2bf(a1.z); v[7] = f2bf(a1.w);
            *reinterpret_cast<bf16x8*>(&Asf[(r * 64 + scol) ^ ((r & 7) << 3)]) = v;
        }
        #pragma unroll
        for (int p = 0; p < 4; ++p) {
            const int r = p * 32 + srow;
            const int4* ws = reinterpret_cast<const int4*>(
                W + (size_t)(bcol + r) * K_DIM + (k0 + scol));
            int4 b0 = ws[0], b1 = ws[1];
            bf16x8 v;
            v[0] = f2bf((float)b0.x); v[1] = f2bf((float)b0.y);
            v[2] = f2bf((float)b0.z); v[3] = f2bf((float)b0.w);
            v[4] = f2bf((float)b1.x); v[5] = f2bf((float)b1.y);
            v[6] = f2bf((float)b1.z); v[7] = f2bf((float)b1.w);
            *reinterpret_cast<bf16x8*>(&Bsf[(r * 64 + scol) ^ ((r & 7) << 3)]) = v;
        }
        __syncthreads();
        #pragma unroll
        for (int ks = 0; ks < 2; ++ks) {
            const int kb = ks * 32 + koff;
            bf16x8 af[4], bfr[4];
            #pragma unroll
            for (int m = 0; m < 4; ++m) {
                const int r = arow + m * 16;
                af[m] = *reinterpret_cast<const bf16x8*>(&Asf[(r * 64 + kb) ^ ((r & 7) << 3)]);
            }
            #pragma unroll
            for (int n = 0; n < 4; ++n) {
                const int r = brow_f + n * 16;
                bfr[n] = *reinterpret_cast<const bf16x8*>(&Bsf[(r * 64 + kb) ^ ((r & 7) << 3)]);
            }
            #pragma unroll
            for (int m = 0; m < 4; ++m)
                #pragma unroll
                for (int n = 0; n < 4; ++n)
                    acc[m][n] = MFMA16(af[m], bfr[n], acc[m][n]);
        }
    }

    const int orow0 = brow + wrf * 64 + ((lane >> 4) << 2);
    const int ocol0 = bcol + wcf * 64 + (lane & 15);
    #pragma unroll
    for (int n = 0; n < 4; ++n) {
        const float sc = SC[ocol0 + n * 16];
        #pragma unroll
        for (int m = 0; m < 4; ++m)
            #pragma unroll
            for (int j = 0; j < 4; ++j)
                Out[(size_t)(orow0 + m * 16 + j) * N_DIM + (ocol0 + n * 16)]
                    = acc[m][n][j] * sc;
    }
}

extern "C" void kernel_launch(void* const* d_in, const int* in_sizes, int n_in,
                              void* d_out, int out_size, void* d_ws, size_t ws_size,
                              hipStream_t stream) {
    const float* X  = (const float*)d_in[0];   // [8192, 4096] fp32
    const int*   W  = (const int*)d_in[1];     // [11008, 4096] int32 (int8 range)
    const float* SC = (const float*)d_in[2];   // [11008] fp32
    float* Out = (float*)d_out;                // [8192, 11008] fp32

    const size_t xb_bytes = (size_t)M_DIM * K_DIM * 2;
    const size_t wb_bytes = (size_t)N_DIM * K_DIM * 2;
    if (ws_size >= xb_bytes + wb_bytes) {
        short* Xb = (short*)d_ws;
        short* Wb = (short*)((char*)d_ws + xb_bytes);
        cvt_x_bf16<<<2048, 256, 0, stream>>>(X, Xb, (int)((size_t)M_DIM * K_DIM / 8));
        cvt_w_bf16<<<2048, 256, 0, stream>>>(W, Wb, (int)((size_t)N_DIM * K_DIM / 8));
        gemm_bf16_ovl<<<(M_DIM / 256) * (N_DIM / 256), 512, 0, stream>>>(Xb, Wb, SC, Out);
    } else {
        dim3 grid(N_DIM / 128, M_DIM / 128);
        wo_int8_gemm_fused<<<grid, 256, 0, stream>>>(X, W, SC, Out);
    }
}

// Round 6
// 767.109 us; speedup vs baseline: 1.0006x; 1.0006x over previous
//
#include <hip/hip_runtime.h>
#include <hip/hip_bf16.h>

#define M_DIM 8192
#define N_DIM 11008
#define K_DIM 4096

typedef __attribute__((ext_vector_type(8))) short bf16x8;
typedef __attribute__((ext_vector_type(4))) float f32x4;

__device__ __forceinline__ short f2bf(float f) {
    __hip_bfloat16 h = __float2bfloat16(f);  // RNE
    short s;
    __builtin_memcpy(&s, &h, sizeof(s));
    return s;
}

__device__ __forceinline__ void gload_lds16(const void* g, void* l) {
    __builtin_amdgcn_global_load_lds(
        (const __attribute__((address_space(1))) unsigned int*)g,
        (__attribute__((address_space(3))) unsigned int*)l, 16, 0, 0);
}

#define MFMA16(A, Bv, C) __builtin_amdgcn_mfma_f32_16x16x32_bf16((A), (Bv), (C), 0, 0, 0)

// ---------------- pass 1: conversion kernels ----------------

__global__ __launch_bounds__(256)
void cvt_x_bf16(const float* __restrict__ X, short* __restrict__ Xb, int n8) {
    int i = blockIdx.x * blockDim.x + threadIdx.x;
    const int stride = gridDim.x * blockDim.x;
    for (; i < n8; i += stride) {
        const float4* p = reinterpret_cast<const float4*>(X + (size_t)i * 8);
        float4 a = p[0], b = p[1];
        bf16x8 v;
        v[0] = f2bf(a.x); v[1] = f2bf(a.y); v[2] = f2bf(a.z); v[3] = f2bf(a.w);
        v[4] = f2bf(b.x); v[5] = f2bf(b.y); v[6] = f2bf(b.z); v[7] = f2bf(b.w);
        *reinterpret_cast<bf16x8*>(Xb + (size_t)i * 8) = v;
    }
}

__global__ __launch_bounds__(256)
void cvt_w_bf16(const int* __restrict__ W, short* __restrict__ Wb, int n8) {
    int i = blockIdx.x * blockDim.x + threadIdx.x;
    const int stride = gridDim.x * blockDim.x;
    for (; i < n8; i += stride) {
        const int4* p = reinterpret_cast<const int4*>(W + (size_t)i * 8);
        int4 a = p[0], b = p[1];
        bf16x8 v;  // int8-range values exact in bf16
        v[0] = f2bf((float)a.x); v[1] = f2bf((float)a.y);
        v[2] = f2bf((float)a.z); v[3] = f2bf((float)a.w);
        v[4] = f2bf((float)b.x); v[5] = f2bf((float)b.y);
        v[6] = f2bf((float)b.z); v[7] = f2bf((float)b.w);
        *reinterpret_cast<bf16x8*>(Wb + (size_t)i * 8) = v;
    }
}

// ---------------- pass 2: 256x256 bf16 GEMM, overlapped-read schedule ----
// 8 waves (2Mx4N), BK=64, 2 LDS tile-buffers (128 KiB), chunk-XOR swizzle
// via pre-swizzled global_load_lds source. bx-major block ordering within
// XCD chunks (L3: keep A fully resident, ~2 B panels per XCD L2).
// Non-temporal epilogue stores keep the 360 MB output stream out of L3.
// Counted vmcnt(4) at tile end — never drained to 0 in the main loop.

#define STA(T, B, H) do { \
    const short* s_ = gA + (size_t)((H) * 128) * K_DIM + (T) * 64; \
    char* d_ = As + (B) * 32768 + (H) * 16384 + aw; \
    gload_lds16(s_, d_); \
    gload_lds16(s_ + (size_t)64 * K_DIM, d_ + 8192); \
} while (0)

#define STB(T, B, H) do { \
    const short* s_ = gB + (size_t)((H) * 128) * K_DIM + (T) * 64; \
    char* d_ = Bs + (B) * 32768 + (H) * 16384 + aw; \
    gload_lds16(s_, d_); \
    gload_lds16(s_ + (size_t)64 * K_DIM, d_ + 8192); \
} while (0)

// MODE: 0 = steady (issue A t+1, B t+2, vmcnt(4))
//       1 = t==62 (issue A t+1 only, vmcnt(0))
//       2 = t==63 (no issues, no trailing sync)
#define TILE_BODY(T, B, MODE) do { \
    const char* Ab_ = As + (B) * 32768; \
    const char* Bb_ = Bs + (B) * 32768; \
    bf16x8 a0_[4][2], a1_[4][2], b0_[2][2], b1_[2][2]; \
    /* issue a0 (8), b0 (4), b1 (4) reads */ \
    _Pragma("unroll") for (int m = 0; m < 4; ++m) { \
        a0_[m][0] = *(const bf16x8*)(Ab_ + fa + m * 2048 + cs0); \
        a0_[m][1] = *(const bf16x8*)(Ab_ + fa + m * 2048 + cs1); } \
    _Pragma("unroll") for (int n = 0; n < 2; ++n) { \
        b0_[n][0] = *(const bf16x8*)(Bb_ + fb + n * 2048 + cs0); \
        b0_[n][1] = *(const bf16x8*)(Bb_ + fb + n * 2048 + cs1); \
        b1_[n][0] = *(const bf16x8*)(Bb_ + fb + (n + 2) * 2048 + cs0); \
        b1_[n][1] = *(const bf16x8*)(Bb_ + fb + (n + 2) * 2048 + cs1); } \
    if ((MODE) < 2) { STA((T) + 1, 1 - (B), 0); STA((T) + 1, 1 - (B), 1); } \
    /* ph0: m0-3 x n0-1 (overlaps remaining reads) */ \
    __builtin_amdgcn_s_setprio(1); \
    _Pragma("unroll") for (int m = 0; m < 4; ++m) \
    _Pragma("unroll") for (int n = 0; n < 2; ++n) { \
        acc[m][n] = MFMA16(a0_[m][0], b0_[n][0], acc[m][n]); \
        acc[m][n] = MFMA16(a0_[m][1], b0_[n][1], acc[m][n]); } \
    __builtin_amdgcn_s_setprio(0); \
    /* issue a1 (8) reads — overlap ph1 MFMAs */ \
    _Pragma("unroll") for (int m = 0; m < 4; ++m) { \
        a1_[m][0] = *(const bf16x8*)(Ab_ + fa + (m + 4) * 2048 + cs0); \
        a1_[m][1] = *(const bf16x8*)(Ab_ + fa + (m + 4) * 2048 + cs1); } \
    /* ph1: m0-3 x n2-3 */ \
    __builtin_amdgcn_s_setprio(1); \
    _Pragma("unroll") for (int m = 0; m < 4; ++m) \
    _Pragma("unroll") for (int n = 0; n < 2; ++n) { \
        acc[m][n + 2] = MFMA16(a0_[m][0], b1_[n][0], acc[m][n + 2]); \
        acc[m][n + 2] = MFMA16(a0_[m][1], b1_[n][1], acc[m][n + 2]); } \
    __builtin_amdgcn_s_setprio(0); \
    /* all waves' tile-t LDS reads must be SERVICED before B-region rewrite */ \
    asm volatile("s_waitcnt lgkmcnt(0)" ::: "memory"); \
    asm volatile("s_barrier" ::: "memory"); \
    if ((MODE) == 0) STB((T) + 2, (B), 0); \
    /* ph2: m4-7 x n0-1 */ \
    __builtin_amdgcn_s_setprio(1); \
    _Pragma("unroll") for (int m = 0; m < 4; ++m) \
    _Pragma("unroll") for (int n = 0; n < 2; ++n) { \
        acc[m + 4][n] = MFMA16(a1_[m][0], b0_[n][0], acc[m + 4][n]); \
        acc[m + 4][n] = MFMA16(a1_[m][1], b0_[n][1], acc[m + 4][n]); } \
    __builtin_amdgcn_s_setprio(0); \
    if ((MODE) == 0) STB((T) + 2, (B), 1); \
    /* ph3: m4-7 x n2-3 */ \
    __builtin_amdgcn_s_setprio(1); \
    _Pragma("unroll") for (int m = 0; m < 4; ++m) \
    _Pragma("unroll") for (int n = 0; n < 2; ++n) { \
        acc[m + 4][n + 2] = MFMA16(a1_[m][0], b1_[n][0], acc[m + 4][n + 2]); \
        acc[m + 4][n + 2] = MFMA16(a1_[m][1], b1_[n][1], acc[m + 4][n + 2]); } \
    __builtin_amdgcn_s_setprio(0); \
    if ((MODE) < 2) { \
        asm volatile("s_waitcnt lgkmcnt(0)" ::: "memory"); \
        if ((MODE) == 0) asm volatile("s_waitcnt vmcnt(4)" ::: "memory"); \
        else             asm volatile("s_waitcnt vmcnt(0)" ::: "memory"); \
        asm volatile("s_barrier" ::: "memory"); } \
} while (0)

__global__ __launch_bounds__(512, 2)
void gemm_bf16_ovl(const short* __restrict__ Xb, const short* __restrict__ Wb,
                   const float* __restrict__ SC, float* __restrict__ Out)
{
    __shared__ __attribute__((aligned(16))) char smem[131072];
    char* const As = smem;           // [2][256 rows][128 B], chunk-swizzled
    char* const Bs = smem + 65536;

    const int tid  = threadIdx.x;
    const int lane = tid & 63;
    const int w    = tid >> 6;   // 0..7
    const int wr   = w >> 2;     // 0..1
    const int wc   = w & 3;      // 0..3

    // XCD chunking (bijective: 1376 = 8*172) + bx-MAJOR ordering:
    // concurrent B working-set per XCD ~1-2 panels (L2-resident), A shared
    // across all XCDs and L3-resident.
    const int wg  = blockIdx.x;
    const int swz = (wg & 7) * 172 + (wg >> 3);
    const int bx  = swz >> 5;        // 0..42  (column index, advances slowly)
    const int by  = swz & 31;        // 0..31
    const int brow = by * 256;
    const int bcol = bx * 256;

    // staging: lane covers row (w*8 + lane/8), swizzled chunk (lane&7)^(lane>>3)
    const int lr = lane >> 3;
    const int lc = (lane & 7) ^ lr;
    const short* gA = Xb + (size_t)(brow + w * 8 + lr) * K_DIM + (lc << 3);
    const short* gB = Wb + (size_t)(bcol + w * 8 + lr) * K_DIM + (lc << 3);
    const int aw = w * 1024;  // wave rows offset in LDS dest (w*8 rows * 128B)

    // fragment read bases (byte offsets); chunk-XOR matches staging swizzle
    const int fa  = (wr * 128 + (lane & 15)) * 128;
    const int fb  = (wc * 64  + (lane & 15)) * 128;
    const int cs0 = (((lane >> 4) + 0) ^ (lane & 7)) * 16;
    const int cs1 = (((lane >> 4) + 4) ^ (lane & 7)) * 16;

    f32x4 acc[8][4] = {};

    // prologue: tile0 {B0,B1,A0,A1}, tile1 {B0,B1}; certify tile0, B(1) in flight
    STB(0, 0, 0); STB(0, 0, 1); STA(0, 0, 0); STA(0, 0, 1);
    STB(1, 1, 0); STB(1, 1, 1);
    asm volatile("s_waitcnt vmcnt(4)" ::: "memory");
    asm volatile("s_barrier" ::: "memory");

    for (int t = 0; t < 62; t += 2) {
        TILE_BODY(t, 0, 0);
        TILE_BODY(t + 1, 1, 0);
    }
    TILE_BODY(62, 0, 1);
    TILE_BODY(63, 1, 2);

    // epilogue: per-out-channel scale, fp32 NON-TEMPORAL store (keep the
    // 360 MB output stream from evicting operand panels out of L3)
    // C/D layout: col = lane&15, row = (lane>>4)*4 + j
    const int orow0 = brow + wr * 128 + ((lane >> 4) << 2);
    const int ocol0 = bcol + wc * 64 + (lane & 15);
    #pragma unroll
    for (int n = 0; n < 4; ++n) {
        const float sc = SC[ocol0 + n * 16];
        #pragma unroll
        for (int m = 0; m < 8; ++m)
            #pragma unroll
            for (int j = 0; j < 4; ++j)
                __builtin_nontemporal_store(
                    acc[m][n][j] * sc,
                    &Out[(size_t)(orow0 + m * 16 + j) * N_DIM + (ocol0 + n * 16)]);
    }
}

// ---------------- fallback: fused single-pass (if ws too small) ----------------

__global__ __launch_bounds__(256, 2)
void wo_int8_gemm_fused(const float* __restrict__ X, const int* __restrict__ W,
                        const float* __restrict__ SC, float* __restrict__ Out)
{
    __shared__ short Asf[128 * 64];
    __shared__ short Bsf[128 * 64];

    const int tid  = threadIdx.x;
    const int lane = tid & 63;
    const int wid  = tid >> 6;
    const int wrf  = wid >> 1;
    const int wcf  = wid & 1;
    const int brow = blockIdx.y * 128;
    const int bcol = blockIdx.x * 128;
    const int srow = tid >> 3;
    const int scol = (tid & 7) << 3;
    const int arow   = wrf * 64 + (lane & 15);
    const int brow_f = wcf * 64 + (lane & 15);
    const int koff   = (lane >> 4) << 3;

    f32x4 acc[4][4] = {};

    for (int k0 = 0; k0 < K_DIM; k0 += 64) {
        __syncthreads();
        #pragma unroll
        for (int p = 0; p < 4; ++p) {
            const int r = p * 32 + srow;
            const float4* xs = reinterpret_cast<const float4*>(
                X + (size_t)(brow + r) * K_DIM + (k0 + scol));
            float4 a0 = xs[0], a1 = xs[1];
            bf16x8 v;
            v[0] = f2bf(a0.x); v[1] = f2bf(a0.y); v[2] = f2bf(a0.z); v[3] = f2bf(a0.w);
            v[4] = f2bf(a1.x); v[5] = f2bf(a1.y); v[6] = f2bf(a1.z); v[7] = f2bf(a1.w);
            *reinterpret_cast<bf16x8*>(&Asf[(r * 64 + scol) ^ ((r & 7) << 3)]) = v;
        }
        #pragma unroll
        for (int p = 0; p < 4; ++p) {
            const int r = p * 32 + srow;
            const int4* ws = reinterpret_cast<const int4*>(
                W + (size_t)(bcol + r) * K_DIM + (k0 + scol));
            int4 b0 = ws[0], b1 = ws[1];
            bf16x8 v;
            v[0] = f2bf((float)b0.x); v[1] = f2bf((float)b0.y);
            v[2] = f2bf((float)b0.z); v[3] = f2bf((float)b0.w);
            v[4] = f2bf((float)b1.x); v[5] = f2bf((float)b1.y);
            v[6] = f2bf((float)b1.z); v[7] = f2bf((float)b1.w);
            *reinterpret_cast<bf16x8*>(&Bsf[(r * 64 + scol) ^ ((r & 7) << 3)]) = v;
        }
        __syncthreads();
        #pragma unroll
        for (int ks = 0; ks < 2; ++ks) {
            const int kb = ks * 32 + koff;
            bf16x8 af[4], bfr[4];
            #pragma unroll
            for (int m = 0; m < 4; ++m) {
                const int r = arow + m * 16;
                af[m] = *reinterpret_cast<const bf16x8*>(&Asf[(r * 64 + kb) ^ ((r & 7) << 3)]);
            }
            #pragma unroll
            for (int n = 0; n < 4; ++n) {
                const int r = brow_f + n * 16;
                bfr[n] = *reinterpret_cast<const bf16x8*>(&Bsf[(r * 64 + kb) ^ ((r & 7) << 3)]);
            }
            #pragma unroll
            for (int m = 0; m < 4; ++m)
                #pragma unroll
                for (int n = 0; n < 4; ++n)
                    acc[m][n] = MFMA16(af[m], bfr[n], acc[m][n]);
        }
    }

    const int orow0 = brow + wrf * 64 + ((lane >> 4) << 2);
    const int ocol0 = bcol + wcf * 64 + (lane & 15);
    #pragma unroll
    for (int n = 0; n < 4; ++n) {
        const float sc = SC[ocol0 + n * 16];
        #pragma unroll
        for (int m = 0; m < 4; ++m)
            #pragma unroll
            for (int j = 0; j < 4; ++j)
                Out[(size_t)(orow0 + m * 16 + j) * N_DIM + (ocol0 + n * 16)]
                    = acc[m][n][j] * sc;
    }
}

extern "C" void kernel_launch(void* const* d_in, const int* in_sizes, int n_in,
                              void* d_out, int out_size, void* d_ws, size_t ws_size,
                              hipStream_t stream) {
    const float* X  = (const float*)d_in[0];   // [8192, 4096] fp32
    const int*   W  = (const int*)d_in[1];     // [11008, 4096] int32 (int8 range)
    const float* SC = (const float*)d_in[2];   // [11008] fp32
    float* Out = (float*)d_out;                // [8192, 11008] fp32

    const size_t xb_bytes = (size_t)M_DIM * K_DIM * 2;
    const size_t wb_bytes = (size_t)N_DIM * K_DIM * 2;
    if (ws_size >= xb_bytes + wb_bytes) {
        short* Xb = (short*)d_ws;
        short* Wb = (short*)((char*)d_ws + xb_bytes);
        cvt_x_bf16<<<2048, 256, 0, stream>>>(X, Xb, (int)((size_t)M_DIM * K_DIM / 8));
        cvt_w_bf16<<<2048, 256, 0, stream>>>(W, Wb, (int)((size_t)N_DIM * K_DIM / 8));
        gemm_bf16_ovl<<<(M_DIM / 256) * (N_DIM / 256), 512, 0, stream>>>(Xb, Wb, SC, Out);
    } else {
        dim3 grid(N_DIM / 128, M_DIM / 128);
        wo_int8_gemm_fused<<<grid, 256, 0, stream>>>(X, W, SC, Out);
    }
}

// Round 7
// 429.762 us; speedup vs baseline: 1.7861x; 1.7850x over previous
//
#include <hip/hip_runtime.h>
#include <hip/hip_bf16.h>

#define M_DIM 8192
#define N_DIM 11008
#define K_DIM 4096

typedef __attribute__((ext_vector_type(8))) short bf16x8;
typedef __attribute__((ext_vector_type(4))) float f32x4;
typedef __attribute__((ext_vector_type(4))) int i32x4;

__device__ __forceinline__ short f2bf(float f) {
    __hip_bfloat16 h = __float2bfloat16(f);  // RNE
    short s;
    __builtin_memcpy(&s, &h, sizeof(s));
    return s;
}

__device__ __forceinline__ void gload_lds16(const void* g, void* l) {
    __builtin_amdgcn_global_load_lds(
        (const __attribute__((address_space(1))) unsigned int*)g,
        (__attribute__((address_space(3))) unsigned int*)l, 16, 0, 0);
}

#define MFMAI8(A, Bv, C) __builtin_amdgcn_mfma_i32_16x16x64_i8((A), (Bv), (C), 0, 0, 0)
#define MFMA16(A, Bv, C) __builtin_amdgcn_mfma_f32_16x16x32_bf16((A), (Bv), (C), 0, 0, 0)

// ---------------- pass 1a: X fp32 -> i8 per-row dynamic quant ----------------
// One wave per row (4 rows/block). Row absmax -> scale = absmax/127, RNE quant.

__global__ __launch_bounds__(256)
void quant_x_i8(const float* __restrict__ X, char* __restrict__ Xq,
                float* __restrict__ RS) {
    const int row  = blockIdx.x * 4 + (threadIdx.x >> 6);
    const int lane = threadIdx.x & 63;
    const float* xr = X + (size_t)row * K_DIM;

    float4 v[16];
    float am = 0.0f;
    #pragma unroll
    for (int c = 0; c < 16; ++c) {
        v[c] = *reinterpret_cast<const float4*>(xr + c * 256 + lane * 4);
        am = fmaxf(am, fmaxf(fmaxf(fabsf(v[c].x), fabsf(v[c].y)),
                             fmaxf(fabsf(v[c].z), fabsf(v[c].w))));
    }
    #pragma unroll
    for (int off = 1; off < 64; off <<= 1)
        am = fmaxf(am, __shfl_xor(am, off));

    const float inv = 127.0f / am;
    int* xq32 = reinterpret_cast<int*>(Xq + (size_t)row * K_DIM);
    #pragma unroll
    for (int c = 0; c < 16; ++c) {
        int c0 = __float2int_rn(v[c].x * inv);
        int c1 = __float2int_rn(v[c].y * inv);
        int c2 = __float2int_rn(v[c].z * inv);
        int c3 = __float2int_rn(v[c].w * inv);
        xq32[c * 64 + lane] = (c0 & 255) | ((c1 & 255) << 8) |
                              ((c2 & 255) << 16) | (c3 << 24);
    }
    if (lane == 0) RS[row] = am / 127.0f;
}

// ---------------- pass 1b: W int32 -> i8 (exact) ----------------

__global__ __launch_bounds__(256)
void cvt_w_i8(const int* __restrict__ W, char* __restrict__ Wq, int n16) {
    int i = blockIdx.x * blockDim.x + threadIdx.x;
    const int stride = gridDim.x * blockDim.x;
    for (; i < n16; i += stride) {
        const int4* p = reinterpret_cast<const int4*>(W + (size_t)i * 16);
        int4 a = p[0], b = p[1], c = p[2], d = p[3];
        int4 o;
        o.x = (a.x & 255) | ((a.y & 255) << 8) | ((a.z & 255) << 16) | (a.w << 24);
        o.y = (b.x & 255) | ((b.y & 255) << 8) | ((b.z & 255) << 16) | (b.w << 24);
        o.z = (c.x & 255) | ((c.y & 255) << 8) | ((c.z & 255) << 16) | (c.w << 24);
        o.w = (d.x & 255) | ((d.y & 255) << 8) | ((d.z & 255) << 16) | (d.w << 24);
        *reinterpret_cast<int4*>(Wq + (size_t)i * 16) = o;
    }
}

// ---------------- pass 2: 256x256 i8 GEMM, BK=128 ----------------
// Byte-identical tile geometry to the bf16 BK=64 kernel: 32 KB operand tiles,
// 128 B/row, 8 gload_lds16/thread/tile, chunk-XOR swizzle, 4-phase body with
// 16 MFMA (mfma_i32_16x16x64_i8, K=64 per cs) per phase, counted vmcnt(4).

#define STA(T, B, H) do { \
    const char* s_ = gA + (size_t)((H) * 128) * K_DIM + (T) * 128; \
    char* d_ = As + (B) * 32768 + (H) * 16384 + aw; \
    gload_lds16(s_, d_); \
    gload_lds16(s_ + (size_t)64 * K_DIM, d_ + 8192); \
} while (0)

#define STB(T, B, H) do { \
    const char* s_ = gB + (size_t)((H) * 128) * K_DIM + (T) * 128; \
    char* d_ = Bs + (B) * 32768 + (H) * 16384 + aw; \
    gload_lds16(s_, d_); \
    gload_lds16(s_ + (size_t)64 * K_DIM, d_ + 8192); \
} while (0)

// MODE: 0 = steady (issue A t+1, B t+2, vmcnt(4))
//       1 = t==NT-2 (issue A t+1 only, vmcnt(0))
//       2 = t==NT-1 (no issues, no trailing sync)
#define TILE_BODY(T, B, MODE) do { \
    const char* Ab_ = As + (B) * 32768; \
    const char* Bb_ = Bs + (B) * 32768; \
    i32x4 a0_[4][2], a1_[4][2], b0_[2][2], b1_[2][2]; \
    _Pragma("unroll") for (int m = 0; m < 4; ++m) { \
        a0_[m][0] = *(const i32x4*)(Ab_ + fa + m * 2048 + cs0); \
        a0_[m][1] = *(const i32x4*)(Ab_ + fa + m * 2048 + cs1); } \
    _Pragma("unroll") for (int n = 0; n < 2; ++n) { \
        b0_[n][0] = *(const i32x4*)(Bb_ + fb + n * 2048 + cs0); \
        b0_[n][1] = *(const i32x4*)(Bb_ + fb + n * 2048 + cs1); } \
    if ((MODE) < 2) STA((T) + 1, 1 - (B), 0); \
    __builtin_amdgcn_s_barrier(); \
    asm volatile("s_waitcnt lgkmcnt(0)" ::: "memory"); \
    __builtin_amdgcn_s_setprio(1); \
    _Pragma("unroll") for (int m = 0; m < 4; ++m) \
    _Pragma("unroll") for (int n = 0; n < 2; ++n) { \
        acc[m][n] = MFMAI8(a0_[m][0], b0_[n][0], acc[m][n]); \
        acc[m][n] = MFMAI8(a0_[m][1], b0_[n][1], acc[m][n]); } \
    __builtin_amdgcn_s_setprio(0); \
    __builtin_amdgcn_s_barrier(); \
    _Pragma("unroll") for (int n = 0; n < 2; ++n) { \
        b1_[n][0] = *(const i32x4*)(Bb_ + fb + (n + 2) * 2048 + cs0); \
        b1_[n][1] = *(const i32x4*)(Bb_ + fb + (n + 2) * 2048 + cs1); } \
    if ((MODE) < 2) STA((T) + 1, 1 - (B), 1); \
    __builtin_amdgcn_s_barrier(); \
    asm volatile("s_waitcnt lgkmcnt(0)" ::: "memory"); \
    __builtin_amdgcn_s_setprio(1); \
    _Pragma("unroll") for (int m = 0; m < 4; ++m) \
    _Pragma("unroll") for (int n = 0; n < 2; ++n) { \
        acc[m][n + 2] = MFMAI8(a0_[m][0], b1_[n][0], acc[m][n + 2]); \
        acc[m][n + 2] = MFMAI8(a0_[m][1], b1_[n][1], acc[m][n + 2]); } \
    __builtin_amdgcn_s_setprio(0); \
    __builtin_amdgcn_s_barrier(); \
    _Pragma("unroll") for (int m = 0; m < 4; ++m) { \
        a1_[m][0] = *(const i32x4*)(Ab_ + fa + (m + 4) * 2048 + cs0); \
        a1_[m][1] = *(const i32x4*)(Ab_ + fa + (m + 4) * 2048 + cs1); } \
    if ((MODE) == 0) STB((T) + 2, (B), 0); \
    __builtin_amdgcn_s_barrier(); \
    asm volatile("s_waitcnt lgkmcnt(0)" ::: "memory"); \
    __builtin_amdgcn_s_setprio(1); \
    _Pragma("unroll") for (int m = 0; m < 4; ++m) \
    _Pragma("unroll") for (int n = 0; n < 2; ++n) { \
        acc[m + 4][n] = MFMAI8(a1_[m][0], b0_[n][0], acc[m + 4][n]); \
        acc[m + 4][n] = MFMAI8(a1_[m][1], b0_[n][1], acc[m + 4][n]); } \
    __builtin_amdgcn_s_setprio(0); \
    __builtin_amdgcn_s_barrier(); \
    if ((MODE) == 0) STB((T) + 2, (B), 1); \
    __builtin_amdgcn_s_setprio(1); \
    _Pragma("unroll") for (int m = 0; m < 4; ++m) \
    _Pragma("unroll") for (int n = 0; n < 2; ++n) { \
        acc[m + 4][n + 2] = MFMAI8(a1_[m][0], b1_[n][0], acc[m + 4][n + 2]); \
        acc[m + 4][n + 2] = MFMAI8(a1_[m][1], b1_[n][1], acc[m + 4][n + 2]); } \
    __builtin_amdgcn_s_setprio(0); \
    if ((MODE) == 0) asm volatile("s_waitcnt vmcnt(4)" ::: "memory"); \
    if ((MODE) == 1) asm volatile("s_waitcnt vmcnt(0)" ::: "memory"); \
    __builtin_amdgcn_s_barrier(); \
} while (0)

__global__ __launch_bounds__(512, 2)
void gemm_i8(const char* __restrict__ Xq, const char* __restrict__ Wq,
             const float* __restrict__ RS, const float* __restrict__ SC,
             float* __restrict__ Out)
{
    __shared__ __attribute__((aligned(16))) char smem[131072];
    char* const As = smem;           // [2][256 rows][128 B], chunk-swizzled
    char* const Bs = smem + 65536;

    const int tid  = threadIdx.x;
    const int lane = tid & 63;
    const int w    = tid >> 6;   // 0..7
    const int wr   = w >> 2;     // 0..1
    const int wc   = w & 3;      // 0..3

    // XCD-aware bijective swizzle: nwg = 1376 = 8 * 172
    const int wg  = blockIdx.x;
    const int swz = (wg & 7) * 172 + (wg >> 3);
    const int by  = swz / 43;
    const int bx  = swz - by * 43;
    const int brow = by * 256;
    const int bcol = bx * 256;

    // staging: lane covers row (w*8 + lane/8), swizzled 16B chunk (lane&7)^(lane>>3)
    const int lr = lane >> 3;
    const int lc = (lane & 7) ^ lr;
    const char* gA = Xq + (size_t)(brow + w * 8 + lr) * K_DIM + (lc << 4);
    const char* gB = Wq + (size_t)(bcol + w * 8 + lr) * K_DIM + (lc << 4);
    const int aw = w * 1024;  // wave rows offset in LDS dest

    // fragment read bases (byte offsets); chunk-XOR matches staging swizzle
    const int fa  = (wr * 128 + (lane & 15)) * 128;
    const int fb  = (wc * 64  + (lane & 15)) * 128;
    const int cs0 = (((lane >> 4) + 0) ^ (lane & 7)) * 16;  // k 0..63
    const int cs1 = (((lane >> 4) + 4) ^ (lane & 7)) * 16;  // k 64..127

    i32x4 acc[8][4] = {};

    // prologue: tile0 {B,A}, tile1 {B}; certify tile0, B(1) pair in flight
    STB(0, 0, 0); STB(0, 0, 1); STA(0, 0, 0); STA(0, 0, 1);
    STB(1, 1, 0); STB(1, 1, 1);
    asm volatile("s_waitcnt vmcnt(4)" ::: "memory");
    __builtin_amdgcn_s_barrier();

    // NT = K_DIM/128 = 32 tiles
    for (int t = 0; t < 30; t += 2) {
        TILE_BODY(t, 0, 0);
        TILE_BODY(t + 1, 1, 0);
    }
    TILE_BODY(30, 0, 1);
    TILE_BODY(31, 1, 2);

    // epilogue: out = acc * row_scale * col_scale, fp32 non-temporal store
    // C/D layout: col = lane&15, row = (lane>>4)*4 + j
    const int orow0 = brow + wr * 128 + ((lane >> 4) << 2);
    const int ocol0 = bcol + wc * 64 + (lane & 15);
    float rsv[8][4];
    #pragma unroll
    for (int m = 0; m < 8; ++m)
        #pragma unroll
        for (int j = 0; j < 4; ++j)
            rsv[m][j] = RS[orow0 + m * 16 + j];
    #pragma unroll
    for (int n = 0; n < 4; ++n) {
        const float sc = SC[ocol0 + n * 16];
        #pragma unroll
        for (int m = 0; m < 8; ++m)
            #pragma unroll
            for (int j = 0; j < 4; ++j)
                __builtin_nontemporal_store(
                    (float)acc[m][n][j] * (rsv[m][j] * sc),
                    &Out[(size_t)(orow0 + m * 16 + j) * N_DIM + (ocol0 + n * 16)]);
    }
}

// ---------------- fallback: fused bf16 single-pass (if ws too small) ----------------

__global__ __launch_bounds__(256, 2)
void wo_int8_gemm_fused(const float* __restrict__ X, const int* __restrict__ W,
                        const float* __restrict__ SC, float* __restrict__ Out)
{
    __shared__ short Asf[128 * 64];
    __shared__ short Bsf[128 * 64];

    const int tid  = threadIdx.x;
    const int lane = tid & 63;
    const int wid  = tid >> 6;
    const int wrf  = wid >> 1;
    const int wcf  = wid & 1;
    const int brow = blockIdx.y * 128;
    const int bcol = blockIdx.x * 128;
    const int srow = tid >> 3;
    const int scol = (tid & 7) << 3;
    const int arow   = wrf * 64 + (lane & 15);
    const int brow_f = wcf * 64 + (lane & 15);
    const int koff   = (lane >> 4) << 3;

    f32x4 acc[4][4] = {};

    for (int k0 = 0; k0 < K_DIM; k0 += 64) {
        __syncthreads();
        #pragma unroll
        for (int p = 0; p < 4; ++p) {
            const int r = p * 32 + srow;
            const float4* xs = reinterpret_cast<const float4*>(
                X + (size_t)(brow + r) * K_DIM + (k0 + scol));
            float4 a0 = xs[0], a1 = xs[1];
            bf16x8 v;
            v[0] = f2bf(a0.x); v[1] = f2bf(a0.y); v[2] = f2bf(a0.z); v[3] = f2bf(a0.w);
            v[4] = f2bf(a1.x); v[5] = f2bf(a1.y); v[6] = f2bf(a1.z); v[7] = f2bf(a1.w);
            *reinterpret_cast<bf16x8*>(&Asf[(r * 64 + scol) ^ ((r & 7) << 3)]) = v;
        }
        #pragma unroll
        for (int p = 0; p < 4; ++p) {
            const int r = p * 32 + srow;
            const int4* ws = reinterpret_cast<const int4*>(
                W + (size_t)(bcol + r) * K_DIM + (k0 + scol));
            int4 b0 = ws[0], b1 = ws[1];
            bf16x8 v;
            v[0] = f2bf((float)b0.x); v[1] = f2bf((float)b0.y);
            v[2] = f2bf((float)b0.z); v[3] = f2bf((float)b0.w);
            v[4] = f2bf((float)b1.x); v[5] = f2bf((float)b1.y);
            v[6] = f2bf((float)b1.z); v[7] = f2bf((float)b1.w);
            *reinterpret_cast<bf16x8*>(&Bsf[(r * 64 + scol) ^ ((r & 7) << 3)]) = v;
        }
        __syncthreads();
        #pragma unroll
        for (int ks = 0; ks < 2; ++ks) {
            const int kb = ks * 32 + koff;
            bf16x8 af[4], bfr[4];
            #pragma unroll
            for (int m = 0; m < 4; ++m) {
                const int r = arow + m * 16;
                af[m] = *reinterpret_cast<const bf16x8*>(&Asf[(r * 64 + kb) ^ ((r & 7) << 3)]);
            }
            #pragma unroll
            for (int n = 0; n < 4; ++n) {
                const int r = brow_f + n * 16;
                bfr[n] = *reinterpret_cast<const bf16x8*>(&Bsf[(r * 64 + kb) ^ ((r & 7) << 3)]);
            }
            #pragma unroll
            for (int m = 0; m < 4; ++m)
                #pragma unroll
                for (int n = 0; n < 4; ++n)
                    acc[m][n] = MFMA16(af[m], bfr[n], acc[m][n]);
        }
    }

    const int orow0 = brow + wrf * 64 + ((lane >> 4) << 2);
    const int ocol0 = bcol + wcf * 64 + (lane & 15);
    #pragma unroll
    for (int n = 0; n < 4; ++n) {
        const float sc = SC[ocol0 + n * 16];
        #pragma unroll
        for (int m = 0; m < 4; ++m)
            #pragma unroll
            for (int j = 0; j < 4; ++j)
                Out[(size_t)(orow0 + m * 16 + j) * N_DIM + (ocol0 + n * 16)]
                    = acc[m][n][j] * sc;
    }
}

extern "C" void kernel_launch(void* const* d_in, const int* in_sizes, int n_in,
                              void* d_out, int out_size, void* d_ws, size_t ws_size,
                              hipStream_t stream) {
    const float* X  = (const float*)d_in[0];   // [8192, 4096] fp32
    const int*   W  = (const int*)d_in[1];     // [11008, 4096] int32 (int8 range)
    const float* SC = (const float*)d_in[2];   // [11008] fp32
    float* Out = (float*)d_out;                // [8192, 11008] fp32

    const size_t xq_bytes = (size_t)M_DIM * K_DIM;          // 32 MiB
    const size_t wq_bytes = (size_t)N_DIM * K_DIM;          // 43 MiB
    const size_t rs_bytes = (size_t)M_DIM * sizeof(float);  // 32 KiB
    if (ws_size >= xq_bytes + wq_bytes + rs_bytes) {
        char*  Xq = (char*)d_ws;
        char*  Wq = (char*)d_ws + xq_bytes;
        float* RS = (float*)((char*)d_ws + xq_bytes + wq_bytes);
        quant_x_i8<<<M_DIM / 4, 256, 0, stream>>>(X, Xq, RS);
        cvt_w_i8<<<2048, 256, 0, stream>>>(W, Wq, (int)((size_t)N_DIM * K_DIM / 16));
        gemm_i8<<<(M_DIM / 256) * (N_DIM / 256), 512, 0, stream>>>(Xq, Wq, RS, SC, Out);
    } else {
        dim3 grid(N_DIM / 128, M_DIM / 128);
        wo_int8_gemm_fused<<<grid, 256, 0, stream>>>(X, W, SC, Out);
    }
}